// Round 1
// baseline (415.559 us; speedup 1.0000x reference)
//
#include <hip/hip_runtime.h>
#include <hip/hip_bf16.h>

#define N_NODES 4096
#define F_DIM   512

typedef __attribute__((ext_vector_type(8))) short bf16x8;
typedef __attribute__((ext_vector_type(4))) float f32x4;

__device__ inline short f2bf(float f) {
  union { float f; unsigned u; } c; c.f = f;
  unsigned r = c.u + 0x7fffu + ((c.u >> 16) & 1u);
  return (short)(r >> 16);
}

// ---- K1: v1 = W @ a[:F], v2 = W @ a[F:] (512x512 matvec, wave per row) ----
__global__ void k_compute_v(const float* __restrict__ W, const float* __restrict__ a,
                            float* __restrict__ v1, float* __restrict__ v2) {
  int r = blockIdx.x, l = threadIdx.x;
  float s1 = 0.f, s2 = 0.f;
  for (int c = l; c < F_DIM; c += 64) {
    float w = W[(size_t)r * F_DIM + c];
    s1 += w * a[c];
    s2 += w * a[F_DIM + c];
  }
#pragma unroll
  for (int off = 32; off > 0; off >>= 1) { s1 += __shfl_down(s1, off); s2 += __shfl_down(s2, off); }
  if (l == 0) { v1[r] = s1; v2[r] = s2; }
}

// ---- K2: Wh1 = inp @ v1, Wh2 = inp @ v2 (wave per row) ----
__global__ void k_compute_wh(const float* __restrict__ inp, const float* __restrict__ v1,
                             const float* __restrict__ v2, float* __restrict__ Wh1,
                             float* __restrict__ Wh2) {
  int i = blockIdx.x, l = threadIdx.x;
  float s1 = 0.f, s2 = 0.f;
  for (int c = l; c < F_DIM; c += 64) {
    float x = inp[(size_t)i * F_DIM + c];
    s1 += x * v1[c];
    s2 += x * v2[c];
  }
#pragma unroll
  for (int off = 32; off > 0; off >>= 1) { s1 += __shfl_down(s1, off); s2 += __shfl_down(s2, off); }
  if (l == 0) { Wh1[i] = s1; Wh2[i] = s2; }
}

// ---- K3: transpose fp32 [R][C] -> bf16 [C][R] ----
__global__ void k_transpose_bf16(const float* __restrict__ src, unsigned short* __restrict__ dst,
                                 int R, int C) {
  __shared__ float tile[32][33];
  int c0 = blockIdx.x * 32, r0 = blockIdx.y * 32;
  int tx = threadIdx.x, ty = threadIdx.y;
#pragma unroll
  for (int i = ty; i < 32; i += 8)
    tile[i][tx] = src[(size_t)(r0 + i) * C + c0 + tx];
  __syncthreads();
#pragma unroll
  for (int i = ty; i < 32; i += 8)
    dst[(size_t)(c0 + i) * R + r0 + tx] = (unsigned short)f2bf(tile[tx][i]);
}

// ---- K4: fused masked softmax (pos+neg, no max-subtract) + PV via MFMA ----
// grid (64, 4): blockIdx.x -> 64-row block, blockIdx.y -> 128-col chunk of F.
// 4 waves; wave w owns rows [bx*64 + w*16, +16), all 128 cols of the chunk.
__global__ __launch_bounds__(256) void k_flash(
    const float* __restrict__ adj, const float* __restrict__ Wh1,
    const float* __restrict__ Wh2, const unsigned short* __restrict__ inpT,
    unsigned short* __restrict__ hp, unsigned short* __restrict__ hpn) {
  int tid = threadIdx.x;
  int lane = tid & 63, wave = tid >> 6;
  int row = lane & 15, kg = lane >> 4;          // A-frag: row = lane&15, k-chunk = lane>>4
  int itile = blockIdx.x * 64 + wave * 16;
  int fbase = blockIdx.y * 128;
  int i = itile + row;
  float wh1 = Wh1[i];
  const float* adjp = adj + (size_t)i * N_NODES + kg * 8;
  const float* wh2p = Wh2 + kg * 8;
  f32x4 accp[8] = {}, accn[8] = {};
  float sp = 0.f, sn = 0.f;

  for (int j0 = 0; j0 < N_NODES; j0 += 32) {
    float4 a0 = *(const float4*)(adjp + j0);
    float4 a1 = *(const float4*)(adjp + j0 + 4);
    float4 w0 = *(const float4*)(wh2p + j0);
    float4 w1 = *(const float4*)(wh2p + j0 + 4);
    float av[8] = {a0.x, a0.y, a0.z, a0.w, a1.x, a1.y, a1.z, a1.w};
    float wv[8] = {w0.x, w0.y, w0.z, w0.w, w1.x, w1.y, w1.z, w1.w};
    bf16x8 pp, pn;
#pragma unroll
    for (int r = 0; r < 8; r++) {
      float s = wh1 + wv[r];
      float e = s > 0.f ? s : 0.2f * s;
      float pe = 0.f, ne = 0.f;
      if (av[r] > 0.f) { pe = __expf(e); ne = __expf(-e); }
      sp += pe; sn += ne;
      pp[r] = f2bf(pe);
      pn[r] = f2bf(ne);
    }
    const unsigned short* bptr = inpT + (size_t)(fbase + row) * N_NODES + j0 + kg * 8;
#pragma unroll
    for (int n = 0; n < 8; n++) {
      bf16x8 b = *(const bf16x8*)(bptr + (size_t)n * 16 * N_NODES);
      accp[n] = __builtin_amdgcn_mfma_f32_16x16x32_bf16(pp, b, accp[n], 0, 0, 0);
      accn[n] = __builtin_amdgcn_mfma_f32_16x16x32_bf16(pn, b, accn[n], 0, 0, 0);
    }
  }

  // full row sums: lanes {row, row+16, row+32, row+48} hold partials for row (lane&15)
  sp += __shfl_xor(sp, 16); sp += __shfl_xor(sp, 32);
  sn += __shfl_xor(sn, 16); sn += __shfl_xor(sn, 32);

#pragma unroll
  for (int r = 0; r < 4; r++) {
    int orow = kg * 4 + r;                       // D layout: row = (lane>>4)*4 + r, col = lane&15
    float rp = 1.f / __shfl(sp, orow);
    float rn = -1.f / __shfl(sn, orow);
#pragma unroll
    for (int n = 0; n < 8; n++) {
      size_t o = (size_t)(itile + orow) * F_DIM + fbase + n * 16 + row;
      hp[o]  = (unsigned short)f2bf(accp[n][r] * rp);
      hpn[o] = (unsigned short)f2bf(accn[n][r] * rn);
    }
  }
}

// ---- K5: out = elu(hp @ wtrans[:512] + hpn @ wtrans[512:]) via MFMA ----
// grid (64, 4), same tiling as k_flash.
__global__ __launch_bounds__(256) void k_out_gemm(
    const unsigned short* __restrict__ hp, const unsigned short* __restrict__ hpn,
    const unsigned short* __restrict__ wtT, float* __restrict__ out) {
  int tid = threadIdx.x;
  int lane = tid & 63, wave = tid >> 6;
  int row = lane & 15, kg = lane >> 4;
  int itile = blockIdx.x * 64 + wave * 16;
  int fbase = blockIdx.y * 128;
  f32x4 acc[8] = {};
  const unsigned short* ap1 = hp  + (size_t)(itile + row) * F_DIM + kg * 8;
  const unsigned short* ap2 = hpn + (size_t)(itile + row) * F_DIM + kg * 8;
  const unsigned short* bp  = wtT + (size_t)(fbase + row) * 1024 + kg * 8;

  for (int k0 = 0; k0 < F_DIM; k0 += 32) {
    bf16x8 va1 = *(const bf16x8*)(ap1 + k0);
    bf16x8 va2 = *(const bf16x8*)(ap2 + k0);
#pragma unroll
    for (int n = 0; n < 8; n++) {
      bf16x8 b1 = *(const bf16x8*)(bp + (size_t)n * 16 * 1024 + k0);
      bf16x8 b2 = *(const bf16x8*)(bp + (size_t)n * 16 * 1024 + k0 + F_DIM);
      acc[n] = __builtin_amdgcn_mfma_f32_16x16x32_bf16(va1, b1, acc[n], 0, 0, 0);
      acc[n] = __builtin_amdgcn_mfma_f32_16x16x32_bf16(va2, b2, acc[n], 0, 0, 0);
    }
  }
#pragma unroll
  for (int r = 0; r < 4; r++) {
    int orow = kg * 4 + r;
#pragma unroll
    for (int n = 0; n < 8; n++) {
      float x = acc[n][r];
      float y = x > 0.f ? x : (__expf(x) - 1.f);
      out[(size_t)(itile + orow) * F_DIM + fbase + n * 16 + row] = y;
    }
  }
}

extern "C" void kernel_launch(void* const* d_in, const int* in_sizes, int n_in,
                              void* d_out, int out_size, void* d_ws, size_t ws_size,
                              hipStream_t stream) {
  (void)in_sizes; (void)n_in; (void)out_size; (void)ws_size;
  const float* inp    = (const float*)d_in[0];   // [4096, 512]
  const float* adj    = (const float*)d_in[1];   // [4096, 4096]
  const float* W      = (const float*)d_in[2];   // [512, 512]
  const float* a      = (const float*)d_in[3];   // [1024]
  const float* wtrans = (const float*)d_in[4];   // [1024, 512]
  float* out = (float*)d_out;                    // [4096, 512]

  float* v1  = (float*)d_ws;                     // 512
  float* v2  = v1 + 512;                         // 512
  float* Wh1 = v2 + 512;                         // 4096
  float* Wh2 = Wh1 + 4096;                       // 4096
  unsigned short* inpT = (unsigned short*)(Wh2 + 4096);  // [512][4096] bf16
  unsigned short* wtT  = inpT + (size_t)512 * 4096;      // [512][1024] bf16
  unsigned short* hp   = wtT + (size_t)512 * 1024;       // [4096][512] bf16
  unsigned short* hpn  = hp + (size_t)4096 * 512;        // [4096][512] bf16
  // total ws: ~13.7 MB

  k_compute_v<<<512, 64, 0, stream>>>(W, a, v1, v2);
  k_compute_wh<<<4096, 64, 0, stream>>>(inp, v1, v2, Wh1, Wh2);
  k_transpose_bf16<<<dim3(F_DIM / 32, N_NODES / 32), dim3(32, 8), 0, stream>>>(inp, inpT, N_NODES, F_DIM);
  k_transpose_bf16<<<dim3(F_DIM / 32, 1024 / 32), dim3(32, 8), 0, stream>>>(wtrans, wtT, 1024, F_DIM);
  k_flash<<<dim3(64, 4), 256, 0, stream>>>(adj, Wh1, Wh2, inpT, hp, hpn);
  k_out_gemm<<<dim3(64, 4), 256, 0, stream>>>(hp, hpn, wtT, out);
}

// Round 2
// 333.234 us; speedup vs baseline: 1.2470x; 1.2470x over previous
//
#include <hip/hip_runtime.h>
#include <hip/hip_bf16.h>

#define N_NODES 4096
#define F_DIM   512

typedef __attribute__((ext_vector_type(8))) short bf16x8;
typedef __attribute__((ext_vector_type(4))) float f32x4;

__device__ inline unsigned short f2bf(float f) {
  union { float f; unsigned u; } c; c.f = f;
  unsigned r = c.u + 0x7fffu + ((c.u >> 16) & 1u);
  return (unsigned short)(r >> 16);
}

// ---- K1: v1 = W @ a[:F], v2 = W @ a[F:] ----
__global__ void k_compute_v(const float* __restrict__ W, const float* __restrict__ a,
                            float* __restrict__ v1, float* __restrict__ v2) {
  int r = blockIdx.x, l = threadIdx.x;
  float s1 = 0.f, s2 = 0.f;
  for (int c = l; c < F_DIM; c += 64) {
    float w = W[(size_t)r * F_DIM + c];
    s1 += w * a[c];
    s2 += w * a[F_DIM + c];
  }
#pragma unroll
  for (int off = 32; off > 0; off >>= 1) { s1 += __shfl_down(s1, off); s2 += __shfl_down(s2, off); }
  if (l == 0) { v1[r] = s1; v2[r] = s2; }
}

// ---- K2: Wh1 = inp @ v1, Wh2 = inp @ v2 ----
__global__ void k_compute_wh(const float* __restrict__ inp, const float* __restrict__ v1,
                             const float* __restrict__ v2, float* __restrict__ Wh1,
                             float* __restrict__ Wh2) {
  int i = blockIdx.x, l = threadIdx.x;
  float s1 = 0.f, s2 = 0.f;
  for (int c = l; c < F_DIM; c += 64) {
    float x = inp[(size_t)i * F_DIM + c];
    s1 += x * v1[c];
    s2 += x * v2[c];
  }
#pragma unroll
  for (int off = 32; off > 0; off >>= 1) { s1 += __shfl_down(s1, off); s2 += __shfl_down(s2, off); }
  if (l == 0) { Wh1[i] = s1; Wh2[i] = s2; }
}

// ---- K3: transpose fp32 [R][C] -> bf16 [C][R] ----
__global__ void k_transpose_bf16(const float* __restrict__ src, unsigned short* __restrict__ dst,
                                 int R, int C) {
  __shared__ float tile[32][33];
  int c0 = blockIdx.x * 32, r0 = blockIdx.y * 32;
  int tx = threadIdx.x, ty = threadIdx.y;
#pragma unroll
  for (int i = ty; i < 32; i += 8)
    tile[i][tx] = src[(size_t)(r0 + i) * C + c0 + tx];
  __syncthreads();
#pragma unroll
  for (int i = ty; i < 32; i += 8)
    dst[(size_t)(c0 + i) * R + r0 + tx] = f2bf(tile[tx][i]);
}

// ---- K4: cast fp32 row-major -> bf16 row-major (8 elems/thread) ----
__global__ void k_cast_bf16(const float* __restrict__ src, unsigned short* __restrict__ dst) {
  size_t gid = (size_t)blockIdx.x * 256 + threadIdx.x;
  float4 a = *(const float4*)(src + gid * 8);
  float4 b = *(const float4*)(src + gid * 8 + 4);
  bf16x8 v;
  v[0] = (short)f2bf(a.x); v[1] = (short)f2bf(a.y); v[2] = (short)f2bf(a.z); v[3] = (short)f2bf(a.w);
  v[4] = (short)f2bf(b.x); v[5] = (short)f2bf(b.y); v[6] = (short)f2bf(b.z); v[7] = (short)f2bf(b.w);
  *(bf16x8*)(dst + gid * 8) = v;
}

// ---- K5: adj fp32 (0/1) -> bitmask, wave ballot per 64 j ----
__global__ void k_mask(const float* __restrict__ adj, unsigned long long* __restrict__ mask64) {
  size_t gid = (size_t)blockIdx.x * 256 + threadIdx.x;
  size_t wid = gid >> 6;
  int lane = (int)(gid & 63);
  float v = adj[wid * 64 + lane];
  unsigned long long b = __ballot(v > 0.f);
  if (lane == 0) mask64[wid] = b;
}

// ---- K6: Y1T = (inp @ wtrans[:512])^T, Y2T = (inp @ wtrans[512:])^T  (bf16) ----
// 1-wave blocks, tile 16 j-rows x 64 cols, grid (256, 8).
__global__ __launch_bounds__(64) void k_y(const unsigned short* __restrict__ inpB,
                                          const unsigned short* __restrict__ wtT,
                                          unsigned short* __restrict__ Y1T,
                                          unsigned short* __restrict__ Y2T) {
  int lane = threadIdx.x & 63;
  int row = lane & 15, kg = lane >> 4;
  int jt = blockIdx.x * 16, cb = blockIdx.y * 64;
  f32x4 acc1[4] = {}, acc2[4] = {};
  const unsigned short* ap = inpB + (size_t)(jt + row) * F_DIM + kg * 8;
  for (int k0 = 0; k0 < F_DIM; k0 += 32) {
    bf16x8 a = *(const bf16x8*)(ap + k0);
#pragma unroll
    for (int n = 0; n < 4; n++) {
      const unsigned short* bp = wtT + (size_t)(cb + n * 16 + row) * 1024 + kg * 8 + k0;
      bf16x8 b1 = *(const bf16x8*)(bp);
      bf16x8 b2 = *(const bf16x8*)(bp + F_DIM);
      acc1[n] = __builtin_amdgcn_mfma_f32_16x16x32_bf16(a, b1, acc1[n], 0, 0, 0);
      acc2[n] = __builtin_amdgcn_mfma_f32_16x16x32_bf16(a, b2, acc2[n], 0, 0, 0);
    }
  }
#pragma unroll
  for (int r = 0; r < 4; r++) {
#pragma unroll
    for (int n = 0; n < 4; n++) {
      size_t o = (size_t)(cb + n * 16 + row) * N_NODES + jt + kg * 4 + r;
      Y1T[o] = f2bf(acc1[n][r]);
      Y2T[o] = f2bf(acc2[n][r]);
    }
  }
}

// ---- K7: fused masked dual-softmax + PV + output GEMM (pre-multiplied) + elu ----
// out = elu( P+ @ Y1 / sp  -  P- @ Y2 / sn ), P+- = exp(+-leakyrelu(wh1_i+wh2_j)) * mask
// Block: 16 rows x 128 cols; 4 waves split j (1024 each); LDS-combine epilogue.
__global__ __launch_bounds__(256, 4) void k_flash2(
    const unsigned* __restrict__ mask32, const float* __restrict__ Wh1,
    const float* __restrict__ Wh2, const unsigned short* __restrict__ Y1T,
    const unsigned short* __restrict__ Y2T, float* __restrict__ out) {
  __shared__ float cbuf[4][8][64][4];   // 32 KB
  __shared__ float ssum[2][4][16];
  int tid = threadIdx.x;
  int lane = tid & 63, wave = tid >> 6;
  int row = lane & 15, kg = lane >> 4;
  int itile = blockIdx.x * 16;
  int fbase = blockIdx.y * 128;
  int i = itile + row;
  float wh1 = Wh1[i];
  const unsigned* mrow = mask32 + (size_t)i * (N_NODES / 32);
  const unsigned short* b1p = Y1T + (size_t)(fbase + row) * N_NODES + kg * 8;
  const unsigned short* b2p = Y2T + (size_t)(fbase + row) * N_NODES + kg * 8;
  f32x4 accp[8] = {}, accn[8] = {};
  float sp = 0.f, sn = 0.f;
  int jbeg = wave * (N_NODES / 4), jend = jbeg + N_NODES / 4;

  for (int j0 = jbeg; j0 < jend; j0 += 32) {
    unsigned mb = (mrow[j0 >> 5] >> (kg * 8)) & 0xffu;
    float4 w0 = *(const float4*)(Wh2 + j0 + kg * 8);
    float4 w1 = *(const float4*)(Wh2 + j0 + kg * 8 + 4);
    float wv[8] = {w0.x, w0.y, w0.z, w0.w, w1.x, w1.y, w1.z, w1.w};
    bf16x8 pp, pn;
#pragma unroll
    for (int r = 0; r < 8; r++) {
      float s = wh1 + wv[r];
      float e = fmaxf(s, 0.2f * s);        // leaky relu
      float pe = __expf(e);
      float ne = __expf(-e);
      if (!((mb >> r) & 1u)) { pe = 0.f; ne = 0.f; }
      sp += pe; sn += ne;
      pp[r] = (short)f2bf(pe);
      pn[r] = (short)f2bf(ne);
    }
#pragma unroll
    for (int n = 0; n < 8; n++) {
      bf16x8 b1 = *(const bf16x8*)(b1p + (size_t)n * 16 * N_NODES + j0);
      bf16x8 b2 = *(const bf16x8*)(b2p + (size_t)n * 16 * N_NODES + j0);
      accp[n] = __builtin_amdgcn_mfma_f32_16x16x32_bf16(pp, b1, accp[n], 0, 0, 0);
      accn[n] = __builtin_amdgcn_mfma_f32_16x16x32_bf16(pn, b2, accn[n], 0, 0, 0);
    }
  }

  // per-wave partial row sums -> all lanes hold sum for row (lane&15)
  sp += __shfl_xor(sp, 16); sp += __shfl_xor(sp, 32);
  sn += __shfl_xor(sn, 16); sn += __shfl_xor(sn, 32);
  if (lane < 16) { ssum[0][wave][lane] = sp; ssum[1][wave][lane] = sn; }

  // cross-wave combine: positive accumulators
#pragma unroll
  for (int n = 0; n < 8; n++) *(f32x4*)&cbuf[wave][n][lane][0] = accp[n];
  __syncthreads();
  f32x4 cp[8];
#pragma unroll
  for (int n = 0; n < 8; n++)
    cp[n] = *(const f32x4*)&cbuf[0][n][lane][0] + *(const f32x4*)&cbuf[1][n][lane][0]
          + *(const f32x4*)&cbuf[2][n][lane][0] + *(const f32x4*)&cbuf[3][n][lane][0];
  float rsp = ssum[0][0][row] + ssum[0][1][row] + ssum[0][2][row] + ssum[0][3][row];
  float rsn = ssum[1][0][row] + ssum[1][1][row] + ssum[1][2][row] + ssum[1][3][row];
  __syncthreads();
  // negative accumulators
#pragma unroll
  for (int n = 0; n < 8; n++) *(f32x4*)&cbuf[wave][n][lane][0] = accn[n];
  __syncthreads();
  f32x4 cn[8];
#pragma unroll
  for (int n = 0; n < 8; n++)
    cn[n] = *(const f32x4*)&cbuf[0][n][lane][0] + *(const f32x4*)&cbuf[1][n][lane][0]
          + *(const f32x4*)&cbuf[2][n][lane][0] + *(const f32x4*)&cbuf[3][n][lane][0];

#pragma unroll
  for (int r = 0; r < 4; r++) {
    int orow = kg * 4 + r;                  // D layout: row=(lane>>4)*4+r, col=lane&15
    float rp = 1.f / __shfl(rsp, orow);
    float rn = 1.f / __shfl(rsn, orow);
#pragma unroll
    for (int n = 0; n < 8; n++) {
      float v = cp[n][r] * rp - cn[n][r] * rn;
      float y = v > 0.f ? v : (__expf(v) - 1.f);
      out[(size_t)(itile + orow) * F_DIM + fbase + n * 16 + row] = y;
    }
  }
}

extern "C" void kernel_launch(void* const* d_in, const int* in_sizes, int n_in,
                              void* d_out, int out_size, void* d_ws, size_t ws_size,
                              hipStream_t stream) {
  (void)in_sizes; (void)n_in; (void)out_size; (void)ws_size;
  const float* inp    = (const float*)d_in[0];   // [4096, 512]
  const float* adj    = (const float*)d_in[1];   // [4096, 4096]
  const float* W      = (const float*)d_in[2];   // [512, 512]
  const float* a      = (const float*)d_in[3];   // [1024]
  const float* wtrans = (const float*)d_in[4];   // [1024, 512]
  float* out = (float*)d_out;                    // [4096, 512]

  char* ws = (char*)d_ws;
  float* v1   = (float*)ws;                                  // 512
  float* v2   = v1 + 512;                                    // 512
  float* Wh1  = v2 + 512;                                    // 4096
  float* Wh2  = Wh1 + 4096;                                  // 4096
  unsigned long long* mask64 = (unsigned long long*)(ws + 36864);          // 2 MB
  unsigned short* inpB = (unsigned short*)(ws + 36864 + 2097152);          // 4 MB
  unsigned short* wtT  = (unsigned short*)((char*)inpB + 4194304);         // 1 MB
  unsigned short* Y1T  = (unsigned short*)((char*)wtT + 1048576);          // 4 MB
  unsigned short* Y2T  = (unsigned short*)((char*)Y1T + 4194304);          // 4 MB
  // total ~15.1 MB

  k_compute_v<<<512, 64, 0, stream>>>(W, a, v1, v2);
  k_compute_wh<<<4096, 64, 0, stream>>>(inp, v1, v2, Wh1, Wh2);
  k_cast_bf16<<<(4096 * 512 / 8) / 256, 256, 0, stream>>>(inp, inpB);
  k_transpose_bf16<<<dim3(F_DIM / 32, 1024 / 32), dim3(32, 8), 0, stream>>>(wtrans, wtT, 1024, F_DIM);
  k_mask<<<(N_NODES * (N_NODES / 64) * 64) / 256, 256, 0, stream>>>(adj, mask64);
  k_y<<<dim3(256, 8), 64, 0, stream>>>(inpB, wtT, Y1T, Y2T);
  k_flash2<<<dim3(256, 4), 256, 0, stream>>>((const unsigned*)mask64, Wh1, Wh2, Y1T, Y2T, out);
}

// Round 3
// 160.956 us; speedup vs baseline: 2.5818x; 2.0703x over previous
//
#include <hip/hip_runtime.h>
#include <hip/hip_bf16.h>

#define N_NODES 4096
#define F_DIM   512
#define KTOT    8192
#define LOG2E   1.44269504f

typedef __attribute__((ext_vector_type(8))) short bf16x8;
typedef __attribute__((ext_vector_type(4))) float f32x4;

__device__ inline unsigned short f2bf(float f) {
  union { float f; unsigned u; } c; c.f = f;
  unsigned r = c.u + 0x7fffu + ((c.u >> 16) & 1u);
  return (unsigned short)(r >> 16);
}

// ---- K1: v1 = W @ a[:F], v2 = W @ a[F:] ----
__global__ void k_compute_v(const float* __restrict__ W, const float* __restrict__ a,
                            float* __restrict__ v1, float* __restrict__ v2) {
  int r = blockIdx.x, l = threadIdx.x;
  float s1 = 0.f, s2 = 0.f;
  for (int c = l; c < F_DIM; c += 64) {
    float w = W[(size_t)r * F_DIM + c];
    s1 += w * a[c];
    s2 += w * a[F_DIM + c];
  }
#pragma unroll
  for (int off = 32; off > 0; off >>= 1) { s1 += __shfl_down(s1, off); s2 += __shfl_down(s2, off); }
  if (l == 0) { v1[r] = s1; v2[r] = s2; }
}

// ---- K2: Wh = inp @ v, pre-scaled by log2(e) so P uses a single v_exp_f32 ----
__global__ void k_compute_wh(const float* __restrict__ inp, const float* __restrict__ v1,
                             const float* __restrict__ v2, float* __restrict__ Wh1,
                             float* __restrict__ Wh2) {
  int i = blockIdx.x, l = threadIdx.x;
  float s1 = 0.f, s2 = 0.f;
  for (int c = l; c < F_DIM; c += 64) {
    float x = inp[(size_t)i * F_DIM + c];
    s1 += x * v1[c];
    s2 += x * v2[c];
  }
#pragma unroll
  for (int off = 32; off > 0; off >>= 1) { s1 += __shfl_down(s1, off); s2 += __shfl_down(s2, off); }
  if (l == 0) { Wh1[i] = s1 * LOG2E; Wh2[i] = s2 * LOG2E; }
}

// ---- K3: transpose fp32 [R][C] -> bf16 [C][R] ----
__global__ void k_transpose_bf16(const float* __restrict__ src, unsigned short* __restrict__ dst,
                                 int R, int C) {
  __shared__ float tile[32][33];
  int c0 = blockIdx.x * 32, r0 = blockIdx.y * 32;
  int tx = threadIdx.x, ty = threadIdx.y;
#pragma unroll
  for (int i = ty; i < 32; i += 8)
    tile[i][tx] = src[(size_t)(r0 + i) * C + c0 + tx];
  __syncthreads();
#pragma unroll
  for (int i = ty; i < 32; i += 8)
    dst[(size_t)(c0 + i) * R + r0 + tx] = f2bf(tile[tx][i]);
}

// ---- K4: adj fp32 (0/1) -> bitmask ----
__global__ void k_mask(const float* __restrict__ adj, unsigned long long* __restrict__ mask64) {
  size_t gid = (size_t)blockIdx.x * 256 + threadIdx.x;
  size_t wid = gid >> 6;
  int lane = (int)(gid & 63);
  float v = adj[wid * 64 + lane];
  unsigned long long b = __ballot(v > 0.f);
  if (lane == 0) mask64[wid] = b;
}

// ---- K5: YT[512][8192]: YT[f][j] = (inp@wt1)[j][f], YT[f][4096+j] = (inp@wt2)[j][f] ----
__global__ __launch_bounds__(256) void k_y(const float* __restrict__ inp,
                                           const unsigned short* __restrict__ wtT,
                                           unsigned short* __restrict__ YT) {
  int tid = threadIdx.x, l = tid & 63, w = tid >> 6;
  int row = l & 15, kg = l >> 4;
  int jt = blockIdx.x * 64 + w * 16;
  int cb = blockIdx.y * 64;
  f32x4 acc1[4] = {}, acc2[4] = {};
  const float* ap = inp + (size_t)(jt + row) * F_DIM + kg * 8;
  for (int k0 = 0; k0 < F_DIM; k0 += 32) {
    float4 f0 = *(const float4*)(ap + k0);
    float4 f1 = *(const float4*)(ap + k0 + 4);
    bf16x8 a;
    a[0] = (short)f2bf(f0.x); a[1] = (short)f2bf(f0.y); a[2] = (short)f2bf(f0.z); a[3] = (short)f2bf(f0.w);
    a[4] = (short)f2bf(f1.x); a[5] = (short)f2bf(f1.y); a[6] = (short)f2bf(f1.z); a[7] = (short)f2bf(f1.w);
#pragma unroll
    for (int n = 0; n < 4; n++) {
      const unsigned short* bp = wtT + (size_t)(cb + n * 16 + row) * 1024 + kg * 8 + k0;
      bf16x8 b1 = *(const bf16x8*)(bp);
      bf16x8 b2 = *(const bf16x8*)(bp + F_DIM);
      acc1[n] = __builtin_amdgcn_mfma_f32_16x16x32_bf16(a, b1, acc1[n], 0, 0, 0);
      acc2[n] = __builtin_amdgcn_mfma_f32_16x16x32_bf16(a, b2, acc2[n], 0, 0, 0);
    }
  }
#pragma unroll
  for (int r = 0; r < 4; r++) {
#pragma unroll
    for (int n = 0; n < 4; n++) {
      int f = cb + n * 16 + row;
      int j = jt + kg * 4 + r;
      YT[(size_t)f * KTOT + j] = f2bf(acc1[n][r]);
      YT[(size_t)f * KTOT + 4096 + j] = f2bf(acc2[n][r]);
    }
  }
}

// ---- K6: Pcat[i] = [ exp2(e)/sp | -exp2(-e)/sn ] * mask, bf16, pre-normalized ----
__global__ __launch_bounds__(256) void k_p(const unsigned* __restrict__ mask32,
                                           const float* __restrict__ Wh1,
                                           const float* __restrict__ Wh2,
                                           unsigned short* __restrict__ Pcat) {
  int i = blockIdx.x, t = threadIdx.x;
  float w1 = Wh1[i];
  int j0 = t * 16;
  unsigned mbits = (mask32[i * 128 + (t >> 1)] >> ((t & 1) * 16)) & 0xffffu;
  float4 wv0 = *(const float4*)(Wh2 + j0);
  float4 wv1 = *(const float4*)(Wh2 + j0 + 4);
  float4 wv2 = *(const float4*)(Wh2 + j0 + 8);
  float4 wv3 = *(const float4*)(Wh2 + j0 + 12);
  float w2[16] = {wv0.x, wv0.y, wv0.z, wv0.w, wv1.x, wv1.y, wv1.z, wv1.w,
                  wv2.x, wv2.y, wv2.z, wv2.w, wv3.x, wv3.y, wv3.z, wv3.w};
  float pe[16], ne[16];
  float sp = 0.f, sn = 0.f;
#pragma unroll
  for (int r = 0; r < 16; r++) {
    float s = w1 + w2[r];
    float e = fmaxf(s, 0.2f * s);      // leaky-relu (already in log2 domain)
    float p = exp2f(e);
    float n = exp2f(-e);
    if (!((mbits >> r) & 1u)) { p = 0.f; n = 0.f; }
    pe[r] = p; ne[r] = n; sp += p; sn += n;
  }
#pragma unroll
  for (int off = 1; off < 64; off <<= 1) { sp += __shfl_xor(sp, off); sn += __shfl_xor(sn, off); }
  __shared__ float red[2][4];
  int wv = t >> 6, ln = t & 63;
  if (ln == 0) { red[0][wv] = sp; red[1][wv] = sn; }
  __syncthreads();
  sp = red[0][0] + red[0][1] + red[0][2] + red[0][3];
  sn = red[1][0] + red[1][1] + red[1][2] + red[1][3];
  float rp = 1.f / sp;
  float rn = -1.f / sn;   // fold the minus sign of negative_attention here
  bf16x8 o;
#pragma unroll
  for (int r = 0; r < 8; r++) o[r] = (short)f2bf(pe[r] * rp);
  *(bf16x8*)(Pcat + (size_t)i * KTOT + j0) = o;
#pragma unroll
  for (int r = 0; r < 8; r++) o[r] = (short)f2bf(pe[8 + r] * rp);
  *(bf16x8*)(Pcat + (size_t)i * KTOT + j0 + 8) = o;
#pragma unroll
  for (int r = 0; r < 8; r++) o[r] = (short)f2bf(ne[r] * rn);
  *(bf16x8*)(Pcat + (size_t)i * KTOT + 4096 + j0) = o;
#pragma unroll
  for (int r = 0; r < 8; r++) o[r] = (short)f2bf(ne[8 + r] * rn);
  *(bf16x8*)(Pcat + (size_t)i * KTOT + 4096 + j0 + 8) = o;
}

// ---- K7: part[z] = Pcat[:, zK:(z+1)K] @ YT[:, zK:(z+1)K]^T  (m97-style GEMM) ----
// BM=128, BN=64, BK=32; 256 thr / 4 waves; dbuf LDS via global_load_lds with
// pre-swizzled source (slot_phys = slot_log ^ ((row>>1)&3)) -> 2-way max on ds_read.
#define GLOAD16(gp, lp) __builtin_amdgcn_global_load_lds( \
    (const __attribute__((address_space(1))) unsigned int*)(gp), \
    (__attribute__((address_space(3))) unsigned int*)(lp), 16, 0, 0)

__global__ __launch_bounds__(256) void k_pv(const unsigned short* __restrict__ Pcat,
                                            const unsigned short* __restrict__ YT,
                                            float* __restrict__ part, int kchunk) {
  __shared__ unsigned short Abuf[2][128 * 32];
  __shared__ unsigned short Bbuf[2][64 * 32];
  int tid = threadIdx.x;
  int l = tid & 63, w = tid >> 6;
  int bm0 = blockIdx.x * 128, bn0 = blockIdx.y * 64;
  size_t kbase = (size_t)blockIdx.z * kchunk;
  int nsteps = kchunk / 32;

  // staging: phys slot = lane&3 holds logical slot (lane&3)^((row>>1)&3); row = base + (l>>2)
  int klog16 = (((l & 3) ^ ((l >> 3) & 3)) << 4);
  const char* gA = (const char*)Pcat + ((size_t)(bm0 + w * 32 + (l >> 2)) * KTOT + kbase) * 2 + klog16;
  const char* gB = (const char*)YT + ((size_t)(bn0 + w * 16 + (l >> 2)) * KTOT + kbase) * 2 + klog16;

  // frag read: phys slot = kg ^ ((row>>1)&3), row&15 == l&15
  int swz = (((l >> 4) ^ ((l >> 1) & 3)) << 4);
  int arow = (w >> 1) * 64 + (l & 15);
  int brow = (w & 1) * 32 + (l & 15);

  f32x4 acc[4][2] = {};

#define STAGE(buf, st) do { \
    const char* _ga = gA + (size_t)(st) * 64; \
    const char* _gb = gB + (size_t)(st) * 64; \
    char* _la = (char*)&Abuf[buf][0] + w * 2048; \
    char* _lb = (char*)&Bbuf[buf][0] + w * 1024; \
    GLOAD16(_ga, _la); \
    GLOAD16(_ga + 16 * KTOT * 2, _la + 1024); \
    GLOAD16(_gb, _lb); \
  } while (0)

  STAGE(0, 0);
  __syncthreads();
  for (int st = 0; st < nsteps; st++) {
    int cur = st & 1;
    if (st + 1 < nsteps) STAGE(cur ^ 1, st + 1);
    const char* Ab = (const char*)&Abuf[cur][0];
    const char* Bb = (const char*)&Bbuf[cur][0];
    bf16x8 af[4], bfr[2];
#pragma unroll
    for (int mi = 0; mi < 4; mi++)
      af[mi] = *(const bf16x8*)(Ab + (arow + mi * 16) * 64 + swz);
#pragma unroll
    for (int ni = 0; ni < 2; ni++)
      bfr[ni] = *(const bf16x8*)(Bb + (brow + ni * 16) * 64 + swz);
#pragma unroll
    for (int mi = 0; mi < 4; mi++)
#pragma unroll
      for (int ni = 0; ni < 2; ni++)
        acc[mi][ni] = __builtin_amdgcn_mfma_f32_16x16x32_bf16(af[mi], bfr[ni], acc[mi][ni], 0, 0, 0);
    __syncthreads();
  }

  float* po = part + (size_t)blockIdx.z * (N_NODES * F_DIM);
#pragma unroll
  for (int mi = 0; mi < 4; mi++)
#pragma unroll
    for (int ni = 0; ni < 2; ni++)
#pragma unroll
      for (int r = 0; r < 4; r++) {
        int i = bm0 + (w >> 1) * 64 + mi * 16 + (l >> 4) * 4 + r;
        int f = bn0 + (w & 1) * 32 + ni * 16 + (l & 15);
        po[(size_t)i * F_DIM + f] = acc[mi][ni][r];
      }
}

// ---- K8: out = elu(sum of partials) ----
__global__ void k_fin(const float* __restrict__ part, int nparts, float* __restrict__ out) {
  size_t idx = ((size_t)blockIdx.x * 256 + threadIdx.x) * 4;
  float4 v = *(const float4*)(part + idx);
  for (int p = 1; p < nparts; p++) {
    float4 u = *(const float4*)(part + (size_t)p * (N_NODES * F_DIM) + idx);
    v.x += u.x; v.y += u.y; v.z += u.z; v.w += u.w;
  }
  v.x = v.x > 0.f ? v.x : (__expf(v.x) - 1.f);
  v.y = v.y > 0.f ? v.y : (__expf(v.y) - 1.f);
  v.z = v.z > 0.f ? v.z : (__expf(v.z) - 1.f);
  v.w = v.w > 0.f ? v.w : (__expf(v.w) - 1.f);
  *(float4*)(out + idx) = v;
}

extern "C" void kernel_launch(void* const* d_in, const int* in_sizes, int n_in,
                              void* d_out, int out_size, void* d_ws, size_t ws_size,
                              hipStream_t stream) {
  (void)in_sizes; (void)n_in; (void)out_size;
  const float* inp    = (const float*)d_in[0];   // [4096, 512]
  const float* adj    = (const float*)d_in[1];   // [4096, 4096]
  const float* W      = (const float*)d_in[2];   // [512, 512]
  const float* a      = (const float*)d_in[3];   // [1024]
  const float* wtrans = (const float*)d_in[4];   // [1024, 512]
  float* out = (float*)d_out;                    // [4096, 512]

  char* ws = (char*)d_ws;
  float* v1  = (float*)ws;             // 2KB
  float* v2  = (float*)(ws + 2048);
  float* Wh1 = (float*)(ws + 4096);    // 16KB
  float* Wh2 = (float*)(ws + 20480);

  const size_t PSZ = (size_t)N_NODES * F_DIM * 4;   // 8 MB per partial
  // choose K-split by available workspace
  int ksplit = 4;
  while (ksplit > 1) {
    size_t need = 65536 + (size_t)ksplit * PSZ + 8388608 + 67108864;
    if (need <= ws_size) break;
    ksplit >>= 1;
  }
  char* regA = ws + 65536;
  unsigned long long* mask64 = (unsigned long long*)regA;          // 2MB (setup phase)
  unsigned short* wtT  = (unsigned short*)(regA + 2097152);        // 1MB (setup phase)
  float* part = (float*)regA;                                      // ksplit * 8MB (GEMM phase)
  unsigned short* YT   = (unsigned short*)(regA + (size_t)ksplit * PSZ);      // 8MB
  unsigned short* Pcat = (unsigned short*)(regA + (size_t)ksplit * PSZ + 8388608); // 64MB

  int kchunk = KTOT / ksplit;

  k_compute_v<<<512, 64, 0, stream>>>(W, a, v1, v2);
  k_compute_wh<<<4096, 64, 0, stream>>>(inp, v1, v2, Wh1, Wh2);
  k_mask<<<65536, 256, 0, stream>>>(adj, mask64);
  k_transpose_bf16<<<dim3(16, 32), dim3(32, 8), 0, stream>>>(wtrans, wtT, 1024, F_DIM);
  k_y<<<dim3(64, 8), 256, 0, stream>>>(inp, wtT, YT);
  k_p<<<4096, 256, 0, stream>>>((const unsigned*)mask64, Wh1, Wh2, Pcat);
  k_pv<<<dim3(32, 8, ksplit), 256, 0, stream>>>(Pcat, YT, part, kchunk);
  k_fin<<<2048, 256, 0, stream>>>(part, ksplit, out);
}

// Round 4
// 133.312 us; speedup vs baseline: 3.1172x; 1.2074x over previous
//
#include <hip/hip_runtime.h>
#include <hip/hip_bf16.h>

#define N_NODES 4096
#define F_DIM   512
#define KTOT    8192
#define LOG2E   1.44269504f

typedef __attribute__((ext_vector_type(8))) short bf16x8;
typedef __attribute__((ext_vector_type(4))) float f32x4;

__device__ inline unsigned short f2bf(float f) {
  union { float f; unsigned u; } c; c.f = f;
  unsigned r = c.u + 0x7fffu + ((c.u >> 16) & 1u);
  return (unsigned short)(r >> 16);
}

// ---- K1: v1 = W @ a[:F], v2 = W @ a[F:] ----
__global__ void k_compute_v(const float* __restrict__ W, const float* __restrict__ a,
                            float* __restrict__ v1, float* __restrict__ v2) {
  int r = blockIdx.x, l = threadIdx.x;
  float s1 = 0.f, s2 = 0.f;
  for (int c = l; c < F_DIM; c += 64) {
    float w = W[(size_t)r * F_DIM + c];
    s1 += w * a[c];
    s2 += w * a[F_DIM + c];
  }
#pragma unroll
  for (int off = 32; off > 0; off >>= 1) { s1 += __shfl_down(s1, off); s2 += __shfl_down(s2, off); }
  if (l == 0) { v1[r] = s1; v2[r] = s2; }
}

// ---- K2: Wh = inp @ v, pre-scaled by log2(e) so P uses exp2 ----
__global__ void k_compute_wh(const float* __restrict__ inp, const float* __restrict__ v1,
                             const float* __restrict__ v2, float* __restrict__ Wh1,
                             float* __restrict__ Wh2) {
  int i = blockIdx.x, l = threadIdx.x;
  float s1 = 0.f, s2 = 0.f;
  for (int c = l; c < F_DIM; c += 64) {
    float x = inp[(size_t)i * F_DIM + c];
    s1 += x * v1[c];
    s2 += x * v2[c];
  }
#pragma unroll
  for (int off = 32; off > 0; off >>= 1) { s1 += __shfl_down(s1, off); s2 += __shfl_down(s2, off); }
  if (l == 0) { Wh1[i] = s1 * LOG2E; Wh2[i] = s2 * LOG2E; }
}

// ---- K3: transpose fp32 [R][C] -> bf16 [C][R] ----
__global__ void k_transpose_bf16(const float* __restrict__ src, unsigned short* __restrict__ dst,
                                 int R, int C) {
  __shared__ float tile[32][33];
  int c0 = blockIdx.x * 32, r0 = blockIdx.y * 32;
  int tx = threadIdx.x, ty = threadIdx.y;
#pragma unroll
  for (int i = ty; i < 32; i += 8)
    tile[i][tx] = src[(size_t)(r0 + i) * C + c0 + tx];
  __syncthreads();
#pragma unroll
  for (int i = ty; i < 32; i += 8)
    dst[(size_t)(c0 + i) * R + r0 + tx] = f2bf(tile[tx][i]);
}

// ---- K4: YT[512][8192]: YT[f][j] = (inp@wt1)[j][f], YT[f][4096+j] = (inp@wt2)[j][f] ----
__global__ __launch_bounds__(256) void k_y(const float* __restrict__ inp,
                                           const unsigned short* __restrict__ wtT,
                                           unsigned short* __restrict__ YT) {
  int tid = threadIdx.x, l = tid & 63, w = tid >> 6;
  int row = l & 15, kg = l >> 4;
  int jt = blockIdx.x * 64 + w * 16;
  int cb = blockIdx.y * 64;
  f32x4 acc1[4] = {}, acc2[4] = {};
  const float* ap = inp + (size_t)(jt + row) * F_DIM + kg * 8;
  for (int k0 = 0; k0 < F_DIM; k0 += 32) {
    float4 f0 = *(const float4*)(ap + k0);
    float4 f1 = *(const float4*)(ap + k0 + 4);
    bf16x8 a;
    a[0] = (short)f2bf(f0.x); a[1] = (short)f2bf(f0.y); a[2] = (short)f2bf(f0.z); a[3] = (short)f2bf(f0.w);
    a[4] = (short)f2bf(f1.x); a[5] = (short)f2bf(f1.y); a[6] = (short)f2bf(f1.z); a[7] = (short)f2bf(f1.w);
#pragma unroll
    for (int n = 0; n < 4; n++) {
      const unsigned short* bp = wtT + (size_t)(cb + n * 16 + row) * 1024 + kg * 8 + k0;
      bf16x8 b1 = *(const bf16x8*)(bp);
      bf16x8 b2 = *(const bf16x8*)(bp + F_DIM);
      acc1[n] = __builtin_amdgcn_mfma_f32_16x16x32_bf16(a, b1, acc1[n], 0, 0, 0);
      acc2[n] = __builtin_amdgcn_mfma_f32_16x16x32_bf16(a, b2, acc2[n], 0, 0, 0);
    }
  }
  int jb = jt + kg * 4;
#pragma unroll
  for (int n = 0; n < 4; n++) {
    int f = cb + n * 16 + row;
    ushort4 o1, o2;
    o1.x = f2bf(acc1[n][0]); o1.y = f2bf(acc1[n][1]); o1.z = f2bf(acc1[n][2]); o1.w = f2bf(acc1[n][3]);
    o2.x = f2bf(acc2[n][0]); o2.y = f2bf(acc2[n][1]); o2.z = f2bf(acc2[n][2]); o2.w = f2bf(acc2[n][3]);
    *(ushort4*)(YT + (size_t)f * KTOT + jb) = o1;
    *(ushort4*)(YT + (size_t)f * KTOT + 4096 + jb) = o2;
  }
}

// ---- K5: Pcat[i] = [ exp2(e)/sp | -exp2(-e)/sn ] * (adj>0), bf16, pre-normalized ----
// Reads adj directly (mask kernel folded in).
__global__ __launch_bounds__(256) void k_p(const float* __restrict__ adj,
                                           const float* __restrict__ Wh1,
                                           const float* __restrict__ Wh2,
                                           unsigned short* __restrict__ Pcat) {
  int i = blockIdx.x, t = threadIdx.x;
  float w1 = Wh1[i];
  int j0 = t * 16;
  const float* ar = adj + (size_t)i * N_NODES + j0;
  float4 A0 = *(const float4*)(ar);
  float4 A1 = *(const float4*)(ar + 4);
  float4 A2 = *(const float4*)(ar + 8);
  float4 A3 = *(const float4*)(ar + 12);
  float am[16] = {A0.x, A0.y, A0.z, A0.w, A1.x, A1.y, A1.z, A1.w,
                  A2.x, A2.y, A2.z, A2.w, A3.x, A3.y, A3.z, A3.w};
  float4 wv0 = *(const float4*)(Wh2 + j0);
  float4 wv1 = *(const float4*)(Wh2 + j0 + 4);
  float4 wv2 = *(const float4*)(Wh2 + j0 + 8);
  float4 wv3 = *(const float4*)(Wh2 + j0 + 12);
  float w2[16] = {wv0.x, wv0.y, wv0.z, wv0.w, wv1.x, wv1.y, wv1.z, wv1.w,
                  wv2.x, wv2.y, wv2.z, wv2.w, wv3.x, wv3.y, wv3.z, wv3.w};
  float pe[16], ne[16];
  float sp = 0.f, sn = 0.f;
#pragma unroll
  for (int r = 0; r < 16; r++) {
    float s = w1 + w2[r];
    float e = fmaxf(s, 0.2f * s);      // leaky-relu (log2 domain)
    float p = exp2f(e);
    float n = exp2f(-e);
    if (!(am[r] > 0.f)) { p = 0.f; n = 0.f; }
    pe[r] = p; ne[r] = n; sp += p; sn += n;
  }
#pragma unroll
  for (int off = 1; off < 64; off <<= 1) { sp += __shfl_xor(sp, off); sn += __shfl_xor(sn, off); }
  __shared__ float red[2][4];
  int wv = t >> 6, ln = t & 63;
  if (ln == 0) { red[0][wv] = sp; red[1][wv] = sn; }
  __syncthreads();
  sp = red[0][0] + red[0][1] + red[0][2] + red[0][3];
  sn = red[1][0] + red[1][1] + red[1][2] + red[1][3];
  float rp = 1.f / sp;
  float rn = -1.f / sn;   // fold negative_attention's minus sign
  bf16x8 o;
#pragma unroll
  for (int r = 0; r < 8; r++) o[r] = (short)f2bf(pe[r] * rp);
  *(bf16x8*)(Pcat + (size_t)i * KTOT + j0) = o;
#pragma unroll
  for (int r = 0; r < 8; r++) o[r] = (short)f2bf(pe[8 + r] * rp);
  *(bf16x8*)(Pcat + (size_t)i * KTOT + j0 + 8) = o;
#pragma unroll
  for (int r = 0; r < 8; r++) o[r] = (short)f2bf(ne[r] * rn);
  *(bf16x8*)(Pcat + (size_t)i * KTOT + 4096 + j0) = o;
#pragma unroll
  for (int r = 0; r < 8; r++) o[r] = (short)f2bf(ne[8 + r] * rn);
  *(bf16x8*)(Pcat + (size_t)i * KTOT + 4096 + j0 + 8) = o;
}

// ---- K6: part[z] = Pcat[:, zK:(z+1)K] @ YT[:, zK:(z+1)K]^T  (m97 128x128 GEMM) ----
// 4 waves 2x2, wave = 64x64 out (acc[4][4]); BK=32; dbuf LDS; global_load_lds w=16;
// XOR-swizzle: phys 16B seg = seg ^ ((row>>1)&3) on both stage-src and ds_read.
#define GLOAD16(gp, lp) __builtin_amdgcn_global_load_lds( \
    (const __attribute__((address_space(1))) unsigned int*)(gp), \
    (__attribute__((address_space(3))) unsigned int*)(lp), 16, 0, 0)

__global__ __launch_bounds__(256) void k_pv(const unsigned short* __restrict__ Pcat,
                                            const unsigned short* __restrict__ YT,
                                            float* __restrict__ part, int kchunk) {
  __shared__ unsigned short Ab[2][128 * 32];
  __shared__ unsigned short Bb[2][128 * 32];
  int t = threadIdx.x;
  int l = t & 63, w = t >> 6;
  int la = l & 15, kg = l >> 4;
  int wr = w >> 1, wc = w & 1;
  int bm0 = blockIdx.x * 128, bn0 = blockIdx.y * 128;
  size_t kbase = (size_t)blockIdx.z * kchunk;
  int nsteps = kchunk / 32;

  // staging: thread t covers rows (t>>2) and 64+(t>>2), phys seg t&3 holds
  // logical seg (t&3)^((row>>1)&3); +64 rows doesn't change the swizzle.
  int seg = ((t & 3) ^ ((t >> 3) & 3)) << 4;
  const char* gA = (const char*)Pcat + ((size_t)(bm0 + (t >> 2)) * KTOT + kbase) * 2 + seg;
  const char* gB = (const char*)YT   + ((size_t)(bn0 + (t >> 2)) * KTOT + kbase) * 2 + seg;
  const size_t rstep = (size_t)64 * KTOT * 2;

  // frag reads: row stride 64B; phys seg = kg ^ ((la>>1)&3) (uniform over mi/ni)
  int aswz = (kg ^ ((la >> 1) & 3)) << 4;
  int abase = (wr * 64 + la) * 64 + aswz;
  int bbase = (wc * 64 + la) * 64 + aswz;

  f32x4 acc[4][4] = {};

#define STAGE(buf, st) do { \
    const char* _ga = gA + (size_t)(st) * 64; \
    const char* _gb = gB + (size_t)(st) * 64; \
    char* _la = (char*)&Ab[buf][0] + w * 1024; \
    char* _lb = (char*)&Bb[buf][0] + w * 1024; \
    GLOAD16(_ga, _la); \
    GLOAD16(_ga + rstep, _la + 4096); \
    GLOAD16(_gb, _lb); \
    GLOAD16(_gb + rstep, _lb + 4096); \
  } while (0)

  STAGE(0, 0);
  __syncthreads();
  for (int st = 0; st < nsteps; st++) {
    int cur = st & 1;
    if (st + 1 < nsteps) STAGE(cur ^ 1, st + 1);
    const char* Abp = (const char*)&Ab[cur][0];
    const char* Bbp = (const char*)&Bb[cur][0];
    bf16x8 af[4], bfr[4];
#pragma unroll
    for (int mi = 0; mi < 4; mi++) af[mi] = *(const bf16x8*)(Abp + abase + mi * 16 * 64);
#pragma unroll
    for (int ni = 0; ni < 4; ni++) bfr[ni] = *(const bf16x8*)(Bbp + bbase + ni * 16 * 64);
#pragma unroll
    for (int mi = 0; mi < 4; mi++)
#pragma unroll
      for (int ni = 0; ni < 4; ni++)
        acc[mi][ni] = __builtin_amdgcn_mfma_f32_16x16x32_bf16(af[mi], bfr[ni], acc[mi][ni], 0, 0, 0);
    __syncthreads();
  }

  float* po = part + (size_t)blockIdx.z * (N_NODES * F_DIM);
#pragma unroll
  for (int mi = 0; mi < 4; mi++)
#pragma unroll
    for (int ni = 0; ni < 4; ni++)
#pragma unroll
      for (int r = 0; r < 4; r++) {
        int i_ = bm0 + wr * 64 + mi * 16 + kg * 4 + r;
        int f_ = bn0 + wc * 64 + ni * 16 + la;
        po[(size_t)i_ * F_DIM + f_] = acc[mi][ni][r];
      }
}

// ---- K7: out = elu(sum of partials) ----
__global__ void k_fin(const float* __restrict__ part, int nparts, float* __restrict__ out) {
  size_t idx = ((size_t)blockIdx.x * 256 + threadIdx.x) * 4;
  float4 v = *(const float4*)(part + idx);
  for (int p = 1; p < nparts; p++) {
    float4 u = *(const float4*)(part + (size_t)p * (N_NODES * F_DIM) + idx);
    v.x += u.x; v.y += u.y; v.z += u.z; v.w += u.w;
  }
  v.x = v.x > 0.f ? v.x : (__expf(v.x) - 1.f);
  v.y = v.y > 0.f ? v.y : (__expf(v.y) - 1.f);
  v.z = v.z > 0.f ? v.z : (__expf(v.z) - 1.f);
  v.w = v.w > 0.f ? v.w : (__expf(v.w) - 1.f);
  *(float4*)(out + idx) = v;
}

extern "C" void kernel_launch(void* const* d_in, const int* in_sizes, int n_in,
                              void* d_out, int out_size, void* d_ws, size_t ws_size,
                              hipStream_t stream) {
  (void)in_sizes; (void)n_in; (void)out_size;
  const float* inp    = (const float*)d_in[0];   // [4096, 512]
  const float* adj    = (const float*)d_in[1];   // [4096, 4096]
  const float* W      = (const float*)d_in[2];   // [512, 512]
  const float* a      = (const float*)d_in[3];   // [1024]
  const float* wtrans = (const float*)d_in[4];   // [1024, 512]
  float* out = (float*)d_out;                    // [4096, 512]

  char* ws = (char*)d_ws;
  float* v1  = (float*)ws;             // 2KB
  float* v2  = (float*)(ws + 2048);
  float* Wh1 = (float*)(ws + 4096);    // 16KB
  float* Wh2 = (float*)(ws + 20480);

  const size_t PSZ = (size_t)N_NODES * F_DIM * 4;   // 8 MB per partial
  int ksplit = 4;
  while (ksplit > 1) {
    size_t need = 65536 + (size_t)ksplit * PSZ + 8388608 + 67108864;
    if (need <= ws_size) break;
    ksplit >>= 1;
  }
  char* regA = ws + 65536;
  unsigned short* wtT  = (unsigned short*)regA;                    // 1MB (setup, aliased by part later)
  float* part = (float*)regA;                                      // ksplit * 8MB
  unsigned short* YT   = (unsigned short*)(regA + (size_t)ksplit * PSZ);           // 8MB
  unsigned short* Pcat = (unsigned short*)(regA + (size_t)ksplit * PSZ + 8388608); // 64MB

  int kchunk = KTOT / ksplit;

  k_compute_v<<<512, 64, 0, stream>>>(W, a, v1, v2);
  k_compute_wh<<<4096, 64, 0, stream>>>(inp, v1, v2, Wh1, Wh2);
  k_transpose_bf16<<<dim3(16, 32), dim3(32, 8), 0, stream>>>(wtrans, wtT, 1024, F_DIM);
  k_y<<<dim3(64, 8), 256, 0, stream>>>(inp, wtT, YT);
  k_p<<<4096, 256, 0, stream>>>(adj, Wh1, Wh2, Pcat);
  k_pv<<<dim3(32, 4, ksplit), 256, 0, stream>>>(Pcat, YT, part, kchunk);
  k_fin<<<2048, 256, 0, stream>>>(part, ksplit, out);
}